// Round 18
// baseline (741.057 us; speedup 1.0000x reference)
//
#include <hip/hip_runtime.h>

typedef __attribute__((ext_vector_type(4))) float f32x4;
typedef _Float16 f16;
typedef __attribute__((ext_vector_type(2))) _Float16 f16x2;
typedef __attribute__((ext_vector_type(8))) _Float16 f16x8;

#define T_LEN 2048
#define B_SZ 256
#define FEATN 128
#define H 50
#define H3 150
#define XW_STRIDE 160

#define SFENCE __builtin_amdgcn_sched_barrier(0)

__device__ __forceinline__ float rcpf(float x) { return __builtin_amdgcn_rcpf(x); }

__device__ __forceinline__ float dot2f(f16x2 a, f16x2 b, float c) {
  return __builtin_amdgcn_fdot2(a, b, c, false);
}

// ---------------- Phase 1: xw[m][k] = x[m][:] @ W[:][k]  (f16 out, no bias) ----
__global__ __launch_bounds__(256) void xw_gemm(const float* __restrict__ x,
                                               const float* __restrict__ W,
                                               f16* __restrict__ xw) {
  __shared__ f16 Wt[160 * 136];  // [n][k], row stride 136 halves
  const int tid = threadIdx.x;
  for (int idx = tid; idx < FEATN * H3; idx += 256) {
    int f = idx / H3;
    int n = idx - f * H3;
    Wt[n * 136 + f] = (f16)W[idx];
  }
  for (int idx = tid; idx < 10 * FEATN; idx += 256) {  // zero-pad n = 150..159
    int n = H3 + (idx >> 7);
    int f = idx & 127;
    Wt[n * 136 + f] = (f16)0.f;
  }
  __syncthreads();

  const int wid = tid >> 6;
  const int lane = tid & 63;
  const int l15 = lane & 15;
  const int g = lane >> 4;
  const long row0 = (long)blockIdx.x * 128 + wid * 32;

  f16x8 a[2][4];
#pragma unroll
  for (int sub = 0; sub < 2; ++sub) {
    const float* xp = x + (row0 + sub * 16 + l15) * FEATN + g * 8;
#pragma unroll
    for (int kk = 0; kk < 4; ++kk) {
      f32x4 p0 = *(const f32x4*)(xp + kk * 32);
      f32x4 p1 = *(const f32x4*)(xp + kk * 32 + 4);
      f16x8 v;
      v[0] = (f16)p0[0]; v[1] = (f16)p0[1]; v[2] = (f16)p0[2]; v[3] = (f16)p0[3];
      v[4] = (f16)p1[0]; v[5] = (f16)p1[1]; v[6] = (f16)p1[2]; v[7] = (f16)p1[3];
      a[sub][kk] = v;
    }
  }

  for (int nt = 0; nt < 10; ++nt) {
    const f16* bp = &Wt[(nt * 16 + l15) * 136 + g * 8];
    f16x8 bf0 = *(const f16x8*)(bp);
    f16x8 bf1 = *(const f16x8*)(bp + 32);
    f16x8 bf2 = *(const f16x8*)(bp + 64);
    f16x8 bf3 = *(const f16x8*)(bp + 96);
    f32x4 acc0 = {0.f, 0.f, 0.f, 0.f};
    f32x4 acc1 = {0.f, 0.f, 0.f, 0.f};
    acc0 = __builtin_amdgcn_mfma_f32_16x16x32_f16(a[0][0], bf0, acc0, 0, 0, 0);
    acc0 = __builtin_amdgcn_mfma_f32_16x16x32_f16(a[0][1], bf1, acc0, 0, 0, 0);
    acc0 = __builtin_amdgcn_mfma_f32_16x16x32_f16(a[0][2], bf2, acc0, 0, 0, 0);
    acc0 = __builtin_amdgcn_mfma_f32_16x16x32_f16(a[0][3], bf3, acc0, 0, 0, 0);
    acc1 = __builtin_amdgcn_mfma_f32_16x16x32_f16(a[1][0], bf0, acc1, 0, 0, 0);
    acc1 = __builtin_amdgcn_mfma_f32_16x16x32_f16(a[1][1], bf1, acc1, 0, 0, 0);
    acc1 = __builtin_amdgcn_mfma_f32_16x16x32_f16(a[1][2], bf2, acc1, 0, 0, 0);
    acc1 = __builtin_amdgcn_mfma_f32_16x16x32_f16(a[1][3], bf3, acc1, 0, 0, 0);
    int col = nt * 16 + l15;
    if (col < H3) {
#pragma unroll
      for (int r = 0; r < 4; ++r) {
        long rowA = row0 + g * 4 + r;
        xw[rowA * XW_STRIDE + col] = (f16)acc0[r];
        xw[(rowA + 16) * XW_STRIDE + col] = (f16)acc1[r];
      }
    }
  }
}

// ---------------- Phase 2: 3 waves per row — one gate per wave ---------------
// Wave w (w=0:z, 1:r, 2:h) owns gate columns [w*50, w*50+50): 25 dots/wave,
// U slice = 25 VGPRs (small enough to stay register-resident at last).
// Sync: raw s_barrier + no-clobber lgkmcnt asm + sched_barrier fences (m201
// pattern) -- does NOT drain vmcnt, so each wave's xw prefetch stays in
// flight. Per step: [all: h-bcast read + 25 dots + sigmoid] -> bar1 ->
// [wv2: zz,rr from LDS, tanh+blend, h write] -> bar2.
__global__ __launch_bounds__(192, 1) void gru3(const f16* __restrict__ xw,
                                               const float* __restrict__ U,
                                               const float* __restrict__ bias,
                                               const float* __restrict__ W2,
                                               const float* __restrict__ b2,
                                               float* __restrict__ out) {
  __shared__ __align__(16) f16 h16[64];
  __shared__ float zbuf[64];
  __shared__ float rbuf[64];
  __shared__ float fin[52];
  __shared__ float red[8];
  const int tid = threadIdx.x;
  const int l = tid & 63;
  const int wv = tid >> 6;  // 0,1,2 (wave-uniform)
  const int b = blockIdx.x;
  const int lc = l < H ? l : H - 1;
  const bool act = l < H;
  const long base = (long)b * T_LEN * XW_STRIDE;
  const int goff = wv * H;  // 0 / 50 / 100

  // This wave's U gate-slice, packed f16 pairs over j: 25 VGPRs only.
  f16x2 u2[25];
#pragma unroll
  for (int c = 0; c < 25; ++c) {
    u2[c][0] = (f16)U[(2 * c) * H3 + goff + lc];
    u2[c][1] = (f16)U[(2 * c + 1) * H3 + goff + lc];
  }
  const float b0h = bias[2 * H + lc];  // used by wv2 only
  const float bsum = (wv == 2) ? bias[H3 + 2 * H + lc]
                               : bias[goff + lc] + bias[H3 + goff + lc];

  float hold = 0.f;
  h16[l] = (f16)0.f;  // all waves write same value: benign

  // per-wave xw column prefetch ring (depth 4, immediate offsets)
  const f16* q = xw + base + goff + lc;
  f16 px[4];
#pragma unroll
  for (int p = 0; p < 4; ++p) px[p] = q[p * XW_STRIDE];

  SFENCE;
  asm volatile("s_waitcnt lgkmcnt(0)");
  SFENCE;
  __builtin_amdgcn_s_barrier();  // h16 zeros visible to all waves

  const f16x8* hp8 = (const f16x8*)h16;

#define STEP(P, PF)                                                           \
    {                                                                         \
      f16x8 w0 = hp8[0], w1 = hp8[1], w2 = hp8[2];                            \
      f16x8 w3 = hp8[3], w4 = hp8[4], w5 = hp8[5];                            \
      f16x2 w6 = *(const f16x2*)(h16 + 48);                                   \
      float xv = (float)px[P];                                                \
      if (PF) px[P] = q[(P + 4) * XW_STRIDE];                                 \
      f16x2 hv[25];                                                           \
      hv[0] = __builtin_shufflevector(w0, w0, 0, 1);                          \
      hv[1] = __builtin_shufflevector(w0, w0, 2, 3);                          \
      hv[2] = __builtin_shufflevector(w0, w0, 4, 5);                          \
      hv[3] = __builtin_shufflevector(w0, w0, 6, 7);                          \
      hv[4] = __builtin_shufflevector(w1, w1, 0, 1);                          \
      hv[5] = __builtin_shufflevector(w1, w1, 2, 3);                          \
      hv[6] = __builtin_shufflevector(w1, w1, 4, 5);                          \
      hv[7] = __builtin_shufflevector(w1, w1, 6, 7);                          \
      hv[8] = __builtin_shufflevector(w2, w2, 0, 1);                          \
      hv[9] = __builtin_shufflevector(w2, w2, 2, 3);                          \
      hv[10] = __builtin_shufflevector(w2, w2, 4, 5);                         \
      hv[11] = __builtin_shufflevector(w2, w2, 6, 7);                         \
      hv[12] = __builtin_shufflevector(w3, w3, 0, 1);                         \
      hv[13] = __builtin_shufflevector(w3, w3, 2, 3);                         \
      hv[14] = __builtin_shufflevector(w3, w3, 4, 5);                         \
      hv[15] = __builtin_shufflevector(w3, w3, 6, 7);                         \
      hv[16] = __builtin_shufflevector(w4, w4, 0, 1);                         \
      hv[17] = __builtin_shufflevector(w4, w4, 2, 3);                         \
      hv[18] = __builtin_shufflevector(w4, w4, 4, 5);                         \
      hv[19] = __builtin_shufflevector(w4, w4, 6, 7);                         \
      hv[20] = __builtin_shufflevector(w5, w5, 0, 1);                         \
      hv[21] = __builtin_shufflevector(w5, w5, 2, 3);                         \
      hv[22] = __builtin_shufflevector(w5, w5, 4, 5);                         \
      hv[23] = __builtin_shufflevector(w5, w5, 6, 7);                         \
      hv[24] = w6;                                                            \
      float s0 = bsum, s1 = 0.f;                                              \
      _Pragma("unroll")                                                       \
      for (int p = 0; p < 25; ++p) {                                          \
        if (p & 1) s1 = dot2f(hv[p], u2[p], s1);                              \
        else s0 = dot2f(hv[p], u2[p], s0);                                    \
      }                                                                       \
      float s = s0 + s1;                                                      \
      if (wv == 2) {                                                          \
        float xhb = xv + b0h;                                                 \
        SFENCE;                                                               \
        __builtin_amdgcn_s_barrier(); /* bar1: zz,rr ready */                 \
        float zz = zbuf[l];                                                   \
        float rr = rbuf[l];                                                   \
        float ah = fmaf(rr, s, xhb);                                          \
        float eh = __expf(-2.f * ah);                                         \
        float th = fmaf(2.f, rcpf(1.f + eh), -1.f);                           \
        hold = fmaf(zz, hold - th, th);                                       \
        h16[l] = (f16)hold;                                                   \
        SFENCE;                                                               \
        asm volatile("s_waitcnt lgkmcnt(0)");                                 \
        SFENCE;                                                               \
        __builtin_amdgcn_s_barrier(); /* bar2: h ready */                     \
      } else {                                                                \
        float a = s + xv;                                                     \
        float g = rcpf(1.f + __expf(-a));                                     \
        if (wv == 0) zbuf[l] = g;                                             \
        else rbuf[l] = g;                                                     \
        SFENCE;                                                               \
        asm volatile("s_waitcnt lgkmcnt(0)");                                 \
        SFENCE;                                                               \
        __builtin_amdgcn_s_barrier(); /* bar1 */                              \
        __builtin_amdgcn_s_barrier(); /* bar2 */                              \
      }                                                                       \
    }

  for (int t0 = 0; t0 < T_LEN - 4; t0 += 4) {
    STEP(0, 1) STEP(1, 1) STEP(2, 1) STEP(3, 1)
    q += 4 * XW_STRIDE;
  }
  // final group: no prefetch (avoids OOB reads past the workspace)
  STEP(0, 0) STEP(1, 0) STEP(2, 0) STEP(3, 0)
#undef STEP

  // Epilogue: wv2 holds the final h. Single-wave, in-order LDS -> no barriers.
  if (wv == 2) {
    if (act) {
      fin[l] = hold >= 0.f ? hold : 0.3f * hold;
    }
    if (l < 8) {
      float acc = b2[l];
#pragma unroll
      for (int j = 0; j < H; ++j) acc = fmaf(fin[j], W2[j * 8 + l], acc);
      red[l] = acc;
    }
    if (l < 8) {
      float m = red[0];
#pragma unroll
      for (int i = 1; i < 8; ++i) m = fmaxf(m, red[i]);
      float s = 0.f;
#pragma unroll
      for (int i = 0; i < 8; ++i) s += __expf(red[i] - m);
      out[b * 8 + l] = __expf(red[l] - m) / s;
    }
  }
}

extern "C" void kernel_launch(void* const* d_in, const int* in_sizes, int n_in,
                              void* d_out, int out_size, void* d_ws, size_t ws_size,
                              hipStream_t stream) {
  const float* x = (const float*)d_in[0];
  const float* W = (const float*)d_in[1];
  const float* U = (const float*)d_in[2];
  const float* bias = (const float*)d_in[3];
  const float* W2 = (const float*)d_in[4];
  const float* b2 = (const float*)d_in[5];
  float* out = (float*)d_out;
  f16* xw = (f16*)d_ws;  // [B*T][160] f16, ~168 MB

  xw_gemm<<<4096, 256, 0, stream>>>(x, W, xw);
  gru3<<<256, 192, 0, stream>>>(xw, U, bias, W2, b2, out);
}